// Round 4
// baseline (5984.601 us; speedup 1.0000x reference)
//
#include <hip/hip_runtime.h>

// ---------------- types / helpers ----------------
typedef short bhalf8 __attribute__((ext_vector_type(8)));   // 8 bf16 in 4 VGPRs
typedef unsigned int u32x4 __attribute__((ext_vector_type(4)));
typedef float f32x4  __attribute__((ext_vector_type(4)));

__device__ __forceinline__ unsigned short f2bf(float f) {
    unsigned int u = __builtin_bit_cast(unsigned int, f);
    u = (u + 0x7fffu + ((u >> 16) & 1u)) >> 16;   // RNE
    return (unsigned short)u;
}
__device__ __forceinline__ float bf2f(unsigned short h) {
    unsigned int u = ((unsigned int)h) << 16;
    return __builtin_bit_cast(float, u);
}

// L2-bypass 16B load from the agent coherence point (MALL); base + literal offset
// so the compiler keeps ONE address pair instead of 32.
#define LDG(dst, p, OFF)                                                      \
    asm volatile("global_load_dwordx4 %0, %1, off offset:" #OFF " sc0 sc1"    \
                 : "=v"(dst) : "v"(p))

#define VWAIT0()                                                     \
    do {                                                             \
        asm volatile("s_waitcnt vmcnt(0)" ::: "memory");             \
        __builtin_amdgcn_sched_barrier(0);                           \
    } while (0)

__device__ __forceinline__ unsigned int pkmax(unsigned int a, unsigned int b) {
    unsigned int d;
    asm("v_pk_max_u16 %0, %1, %2" : "=v"(d) : "v"(a), "v"(b));
    return d;
}

#define SEQ   512
#define BATCH 64
#define HID   1024
#define EMBD  1024
#define VOCAB 32000
#define N3H   3072
#define NBLK  64
#define NBUF  4          // h ring buffers (sentinel rotation)

// ---------------- fp32 -> bf16 convert (4 elems/thread) ----------------
__global__ void k_cvt4(const float4* __restrict__ in, ushort4* __restrict__ out, int n4) {
    int i = blockIdx.x * blockDim.x + threadIdx.x;
    if (i < n4) {
        float4 v = in[i];
        ushort4 o;
        o.x = f2bf(v.x); o.y = f2bf(v.y); o.z = f2bf(v.z); o.w = f2bf(v.w);
        out[i] = o;
    }
}

// ---------------- gi GEMM: (32768 x 1024) gathered-A  @  W_ih^T -> bf16 ----------------
__global__ __launch_bounds__(256)
void k_gi(const int* __restrict__ tok, const unsigned short* __restrict__ embb,
          const unsigned short* __restrict__ wih, unsigned short* __restrict__ gi) {
    int nb = blockIdx.x;            // 0..47
    int mb = blockIdx.y;            // 0..127
    int w    = threadIdx.x >> 6;
    int lane = threadIdx.x & 63;
    int q = lane >> 4, l = lane & 15;
    int m0 = mb * 256 + w * 16;
    int n0 = nb * 64;

    const unsigned short* ap[4];
#pragma unroll
    for (int i = 0; i < 4; ++i)
        ap[i] = embb + (size_t)tok[m0 + 64 * i + l] * EMBD + q * 8;

    const unsigned short* bp[4];
#pragma unroll
    for (int j = 0; j < 4; ++j)
        bp[j] = wih + (size_t)(n0 + 16 * j + l) * EMBD + q * 8;

    f32x4 acc[4][4];
#pragma unroll
    for (int i = 0; i < 4; ++i)
#pragma unroll
        for (int j = 0; j < 4; ++j)
            acc[i][j] = (f32x4){0.f, 0.f, 0.f, 0.f};

#pragma unroll 2
    for (int kk = 0; kk < 32; ++kk) {
        int ko = kk * 32;
        bhalf8 bv[4], av[4];
#pragma unroll
        for (int j = 0; j < 4; ++j) bv[j] = *(const bhalf8*)(bp[j] + ko);
#pragma unroll
        for (int i = 0; i < 4; ++i) av[i] = *(const bhalf8*)(ap[i] + ko);
#pragma unroll
        for (int i = 0; i < 4; ++i)
#pragma unroll
            for (int j = 0; j < 4; ++j)
                acc[i][j] = __builtin_amdgcn_mfma_f32_16x16x32_bf16(av[i], bv[j], acc[i][j], 0, 0, 0);
    }
#pragma unroll
    for (int i = 0; i < 4; ++i)
#pragma unroll
        for (int r = 0; r < 4; ++r) {
            size_t mrow = (size_t)(m0 + 64 * i + q * 4 + r) * N3H + n0;
            gi[mrow +  0 + l] = f2bf(acc[i][0][r]);
            gi[mrow + 16 + l] = f2bf(acc[i][1][r]);
            gi[mrow + 32 + l] = f2bf(acc[i][2][r]);
            gi[mrow + 48 + l] = f2bf(acc[i][3][r]);
        }
}

// ---------------- persistent recurrence: sentinel-poll protocol ----------------
// No barrier, no flags. h lives in a 4-deep ring of MALL-bypass buffers,
// host-prepoisoned to 0xFFFF (bf16 NaN; GRU h can never be NaN). A 2-byte
// store is atomically visible, so every polled ushort is either sentinel or
// fresh. Consumers poll the data straight into MFMA A-fragments: ONE fabric
// leg per step instead of three (store-ack + flag + load).
// Buffer reuse proof: owner re-poisons buf[(t+2)&3] during step t; the poll's
// vmcnt(0) drains poison before publish(t+1) issues; a consumer polls buf t+2
// only after confirming t+1 (which implies poison committed). Skew <= 1 step.
__global__ __launch_bounds__(256, 1)
void k_rec(const float* __restrict__ W_hh,
           const unsigned short* __restrict__ gib,
           const float* __restrict__ bih, const float* __restrict__ bhh,
           const float* __restrict__ hidden,
           float* __restrict__ out,
           unsigned short* hbuf) {       // bf16 [NBUF][64*1024], prepoisoned 0xFF
    __shared__ unsigned short sh[49152]; // 96 KB: gates r,z,n for this unit group

    const int tid  = threadIdx.x;
    const int w    = tid >> 6;            // batch quarter 0..3
    const int lane = tid & 63;
    const int q = lane >> 4, l = lane & 15;
    const int G  = blockIdx.x;            // unit group 0..63
    const int m0 = w * 16;
    const int u0 = G * 16 + l;

    // ---- prologue: r,z,n gate fragments -> LDS ([g][kk][lane]*16B) ----
    for (int i = 0; i < 24; ++i) {
        int c  = i * 256 + tid;           // 0..6143
        int g  = c >> 11;                 // 0..2
        int kk = (c >> 6) & 31;
        int ln = c & 63;
        int uu = ln & 15, qq = ln >> 4;
        const float* src = W_hh + (size_t)(g * 1024 + G * 16 + uu) * 1024 + kk * 32 + qq * 8;
        float4 f0 = *(const float4*)src;
        float4 f1 = *(const float4*)(src + 4);
        ushort4 o0, o1;
        o0.x = f2bf(f0.x); o0.y = f2bf(f0.y); o0.z = f2bf(f0.z); o0.w = f2bf(f0.w);
        o1.x = f2bf(f1.x); o1.y = f2bf(f1.y); o1.z = f2bf(f1.z); o1.w = f2bf(f1.w);
        *(ushort4*)&sh[c * 8]     = o0;
        *(ushort4*)&sh[c * 8 + 4] = o1;
    }
    __syncthreads();

    // ---- h0 init + biases; publish h0 into ring buffer 0 ----
    float hp[4];
#pragma unroll
    for (int r = 0; r < 4; ++r) {
        int b = m0 + q * 4 + r;
        float hv = hidden[(size_t)b * HID + u0];
        hp[r] = hv;
        __hip_atomic_store(hbuf + (size_t)b * HID + u0, f2bf(hv),
                           __ATOMIC_RELAXED, __HIP_MEMORY_SCOPE_AGENT);
    }
    float bir = bih[u0], biz = bih[HID + u0], bin = bih[2 * HID + u0];
    float bhr = bhh[u0], bhz = bhh[HID + u0], bhn = bhh[2 * HID + u0];

    // ---- gi for t=0 (b_ih folded in) ----
    float i_r[4], i_z[4], i_n[4];
#pragma unroll
    for (int r = 0; r < 4; ++r) {
        const unsigned short* gp = gib + (size_t)(m0 + q * 4 + r) * N3H + u0;
        i_r[r] = bf2f(gp[0])       + bir;
        i_z[r] = bf2f(gp[HID])     + biz;
        i_n[r] = bf2f(gp[2 * HID]) + bin;
    }

    for (int t = 0; t < SEQ; ++t) {
        const unsigned short* hc = hbuf + (size_t)(t & 3) * (BATCH * HID);
        unsigned short*       hn = hbuf + (size_t)((t + 1) & 3) * (BATCH * HID);
        unsigned short*       hz = hbuf + (size_t)((t + 2) & 3) * (BATCH * HID);
        const unsigned short* hA = hc + (size_t)(m0 + l) * HID + q * 8;

        // gi(t+1) prefetch (compiler-scheduled; drained by the poll's vmcnt(0))
        unsigned short pr[4], pz[4], pn[4];
        if (t + 1 < SEQ) {
            const unsigned short* gt = gib + (size_t)(t + 1) * (BATCH * N3H);
#pragma unroll
            for (int r = 0; r < 4; ++r) {
                const unsigned short* gp = gt + (size_t)(m0 + q * 4 + r) * N3H + u0;
                pr[r] = gp[0]; pz[r] = gp[HID]; pn[r] = gp[2 * HID];
            }
        }

        // ---- sentinel poll: capture h_t straight into A-fragments ----
        bhalf8 hv[32];
        for (;;) {
            LDG(hv[ 0], hA,    0); LDG(hv[ 1], hA,   64); LDG(hv[ 2], hA,  128); LDG(hv[ 3], hA,  192);
            LDG(hv[ 4], hA,  256); LDG(hv[ 5], hA,  320); LDG(hv[ 6], hA,  384); LDG(hv[ 7], hA,  448);
            LDG(hv[ 8], hA,  512); LDG(hv[ 9], hA,  576); LDG(hv[10], hA,  640); LDG(hv[11], hA,  704);
            LDG(hv[12], hA,  768); LDG(hv[13], hA,  832); LDG(hv[14], hA,  896); LDG(hv[15], hA,  960);
            LDG(hv[16], hA, 1024); LDG(hv[17], hA, 1088); LDG(hv[18], hA, 1152); LDG(hv[19], hA, 1216);
            LDG(hv[20], hA, 1280); LDG(hv[21], hA, 1344); LDG(hv[22], hA, 1408); LDG(hv[23], hA, 1472);
            LDG(hv[24], hA, 1536); LDG(hv[25], hA, 1600); LDG(hv[26], hA, 1664); LDG(hv[27], hA, 1728);
            LDG(hv[28], hA, 1792); LDG(hv[29], hA, 1856); LDG(hv[30], hA, 1920); LDG(hv[31], hA, 1984);
            VWAIT0();
            // any-u16 == 0xFFFF detection via pk_max tree (max-half==0xFFFF <=> any sentinel)
            unsigned int m[16];
#pragma unroll
            for (int j = 0; j < 16; ++j) {
                u32x4 c0 = __builtin_bit_cast(u32x4, hv[2 * j]);
                u32x4 c1 = __builtin_bit_cast(u32x4, hv[2 * j + 1]);
                m[j] = pkmax(pkmax(pkmax(c0.x, c0.y), pkmax(c0.z, c0.w)),
                             pkmax(pkmax(c1.x, c1.y), pkmax(c1.z, c1.w)));
            }
#pragma unroll
            for (int s = 8; s > 0; s >>= 1)
#pragma unroll
                for (int j = 0; j < 8; ++j)
                    if (j < s) m[j] = pkmax(m[j], m[j + s]);
            int bad = ((m[0] >> 16) == 0xFFFFu) | ((m[0] & 0xFFFFu) == 0xFFFFu);
            if (!__any(bad)) break;
            __builtin_amdgcn_s_sleep(2);
        }

        // ---- k-loop: pure LDS + MFMA (h already in registers) ----
        f32x4 ar = {0.f, 0.f, 0.f, 0.f}, az = ar, an = ar;
#pragma unroll
        for (int kk = 0; kk < 32; ++kk) {
            bhalf8 brf = *(const bhalf8*)&sh[        kk * 512 + lane * 8];
            bhalf8 bzf = *(const bhalf8*)&sh[16384 + kk * 512 + lane * 8];
            bhalf8 bnf = *(const bhalf8*)&sh[32768 + kk * 512 + lane * 8];
            ar = __builtin_amdgcn_mfma_f32_16x16x32_bf16(hv[kk], brf, ar, 0, 0, 0);
            az = __builtin_amdgcn_mfma_f32_16x16x32_bf16(hv[kk], bzf, az, 0, 0, 0);
            an = __builtin_amdgcn_mfma_f32_16x16x32_bf16(hv[kk], bnf, an, 0, 0, 0);
        }

        // ---- gate math; publish h(t+1) immediately (latency-critical) ----
        float osv[4];
#pragma unroll
        for (int r = 0; r < 4; ++r) {
            int b = m0 + q * 4 + r;
            float rr = 1.f / (1.f + __expf(-(i_r[r] + ar[r] + bhr)));
            float zz = 1.f / (1.f + __expf(-(i_z[r] + az[r] + bhz)));
            float nn = tanhf(i_n[r] + rr * (an[r] + bhn));
            float hv2 = (1.f - zz) * nn + zz * hp[r];
            hp[r] = hv2;
            osv[r] = hv2;
            if (t + 1 < SEQ)
                __hip_atomic_store(hn + (size_t)b * HID + u0, f2bf(hv2),
                                   __ATOMIC_RELAXED, __HIP_MEMORY_SCOPE_AGENT);
        }

        // ---- out stores (never re-read; drain under next poll) ----
        float* ot = out + (size_t)t * (BATCH * HID);
#pragma unroll
        for (int r = 0; r < 4; ++r)
            __builtin_nontemporal_store(osv[r], &ot[(size_t)(m0 + q * 4 + r) * HID + u0]);

        // ---- re-poison ring buffer for step t+2 (own slice only) ----
        if (t + 2 < SEQ) {
#pragma unroll
            for (int r = 0; r < 4; ++r) {
                int b = m0 + q * 4 + r;
                __hip_atomic_store(hz + (size_t)b * HID + u0, (unsigned short)0xFFFFu,
                                   __ATOMIC_RELAXED, __HIP_MEMORY_SCOPE_AGENT);
            }
        }

        // fold bias into next step's gi
#pragma unroll
        for (int r = 0; r < 4; ++r) {
            i_r[r] = bf2f(pr[r]) + bir;
            i_z[r] = bf2f(pz[r]) + biz;
            i_n[r] = bf2f(pn[r]) + bin;
        }
    }
}

// ---------------- launch ----------------
extern "C" void kernel_launch(void* const* d_in, const int* in_sizes, int n_in,
                              void* d_out, int out_size, void* d_ws, size_t ws_size,
                              hipStream_t stream) {
    (void)in_sizes; (void)n_in; (void)out_size;
    const int*   input  = (const int*)  d_in[0];
    const float* hidden = (const float*)d_in[2];
    const float* emb    = (const float*)d_in[3];
    const float* W_ih   = (const float*)d_in[4];
    const float* W_hh   = (const float*)d_in[5];
    const float* b_ih   = (const float*)d_in[6];
    const float* b_hh   = (const float*)d_in[7];
    float* out = (float*)d_out;

    // workspace layout (bytes)
    const size_t EMB_BF  = 0;                                   // 65,536,000
    const size_t WIH_BF  = EMB_BF + (size_t)VOCAB * EMBD * 2;   // +6,291,456
    const size_t GI_OFF  = WIH_BF + (size_t)N3H * EMBD * 2;     // +201,326,592
    const size_t H_OFF   = GI_OFF + (size_t)SEQ * BATCH * N3H * 2;
    const size_t NEED    = H_OFF + (size_t)NBUF * BATCH * HID * 2;
    if (ws_size < NEED) return;

    char* ws = (char*)d_ws;
    unsigned short* embb = (unsigned short*)(ws + EMB_BF);
    unsigned short* wihb = (unsigned short*)(ws + WIH_BF);
    unsigned short* gib  = (unsigned short*)(ws + GI_OFF);
    unsigned short* hbuf = (unsigned short*)(ws + H_OFF);

    // prepoison the whole h ring with bf16 NaN sentinel
    hipMemsetAsync(hbuf, 0xFF, (size_t)NBUF * BATCH * HID * 2, stream);

    {
        int n4 = VOCAB * EMBD / 4;
        k_cvt4<<<(n4 + 255) / 256, 256, 0, stream>>>((const float4*)emb, (ushort4*)embb, n4);
    }
    {
        int n4 = N3H * EMBD / 4;
        k_cvt4<<<(n4 + 255) / 256, 256, 0, stream>>>((const float4*)W_ih, (ushort4*)wihb, n4);
    }

    // input-side GEMM for all timesteps
    k_gi<<<dim3(48, 128), 256, 0, stream>>>(input, embb, wihb, gib);

    // persistent recurrence: 64 blocks (96 KB LDS each -> all co-resident)
    k_rec<<<NBLK, 256, 0, stream>>>(W_hh, gib, b_ih, b_hh, hidden, out, hbuf);
}

// Round 5
// 4573.531 us; speedup vs baseline: 1.3085x; 1.3085x over previous
//
#include <hip/hip_runtime.h>

// ---------------- types / helpers ----------------
typedef short bhalf8 __attribute__((ext_vector_type(8)));   // 8 bf16 in 4 VGPRs
typedef float f32x4  __attribute__((ext_vector_type(4)));

__device__ __forceinline__ unsigned short f2bf(float f) {
    unsigned int u = __builtin_bit_cast(unsigned int, f);
    u = (u + 0x7fffu + ((u >> 16) & 1u)) >> 16;   // RNE
    return (unsigned short)u;
}
__device__ __forceinline__ float bf2f(unsigned short h) {
    unsigned int u = ((unsigned int)h) << 16;
    return __builtin_bit_cast(float, u);
}

// L2-bypass 16B load (reads the agent coherence point / MALL) — fallback mode only.
__device__ __forceinline__ bhalf8 ldg16_bypass(const unsigned short* p) {
    bhalf8 r;
    asm volatile("global_load_dwordx4 %0, %1, off sc0 sc1" : "=v"(r) : "v"(p));
    return r;
}
// write-through no-allocate 2B store: visible at the coherence point once vmcnt
// retires; never allocates a (partially fresh) line in any L2.
__device__ __forceinline__ void stg2_wt(unsigned short* p, unsigned short v) {
    unsigned int vv = v;
    asm volatile("global_store_short %0, %1, off sc0 sc1" :: "v"(p), "v"(vv) : "memory");
}

#define VWAIT0()                                                     \
    do {                                                             \
        asm volatile("s_waitcnt vmcnt(0)" ::: "memory");             \
        __builtin_amdgcn_sched_barrier(0);                           \
    } while (0)

#define SEQ   512
#define BATCH 64
#define HID   1024
#define EMBD  1024
#define VOCAB 32000
#define N3H   3072
#define NBLK  64
#define NBUF  4          // fallback ring depth
#define FLAGSTRIDE 32    // ints; 128B line per flag

// ---------------- fp32 -> bf16 convert (4 elems/thread) ----------------
__global__ void k_cvt4(const float4* __restrict__ in, ushort4* __restrict__ out, int n4) {
    int i = blockIdx.x * blockDim.x + threadIdx.x;
    if (i < n4) {
        float4 v = in[i];
        ushort4 o;
        o.x = f2bf(v.x); o.y = f2bf(v.y); o.z = f2bf(v.z); o.w = f2bf(v.w);
        out[i] = o;
    }
}

// ---------------- gi GEMM: (32768 x 1024) gathered-A  @  W_ih^T -> bf16 ----------------
__global__ __launch_bounds__(256)
void k_gi(const int* __restrict__ tok, const unsigned short* __restrict__ embb,
          const unsigned short* __restrict__ wih, unsigned short* __restrict__ gi) {
    int nb = blockIdx.x;            // 0..47
    int mb = blockIdx.y;            // 0..127
    int w    = threadIdx.x >> 6;
    int lane = threadIdx.x & 63;
    int q = lane >> 4, l = lane & 15;
    int m0 = mb * 256 + w * 16;
    int n0 = nb * 64;

    const unsigned short* ap[4];
#pragma unroll
    for (int i = 0; i < 4; ++i)
        ap[i] = embb + (size_t)tok[m0 + 64 * i + l] * EMBD + q * 8;

    const unsigned short* bp[4];
#pragma unroll
    for (int j = 0; j < 4; ++j)
        bp[j] = wih + (size_t)(n0 + 16 * j + l) * EMBD + q * 8;

    f32x4 acc[4][4];
#pragma unroll
    for (int i = 0; i < 4; ++i)
#pragma unroll
        for (int j = 0; j < 4; ++j)
            acc[i][j] = (f32x4){0.f, 0.f, 0.f, 0.f};

#pragma unroll 2
    for (int kk = 0; kk < 32; ++kk) {
        int ko = kk * 32;
        bhalf8 bv[4], av[4];
#pragma unroll
        for (int j = 0; j < 4; ++j) bv[j] = *(const bhalf8*)(bp[j] + ko);
#pragma unroll
        for (int i = 0; i < 4; ++i) av[i] = *(const bhalf8*)(ap[i] + ko);
#pragma unroll
        for (int i = 0; i < 4; ++i)
#pragma unroll
            for (int j = 0; j < 4; ++j)
                acc[i][j] = __builtin_amdgcn_mfma_f32_16x16x32_bf16(av[i], bv[j], acc[i][j], 0, 0, 0);
    }
#pragma unroll
    for (int i = 0; i < 4; ++i)
#pragma unroll
        for (int r = 0; r < 4; ++r) {
            size_t mrow = (size_t)(m0 + 64 * i + q * 4 + r) * N3H + n0;
            gi[mrow +  0 + l] = f2bf(acc[i][0][r]);
            gi[mrow + 16 + l] = f2bf(acc[i][1][r]);
            gi[mrow + 32 + l] = f2bf(acc[i][2][r]);
            gi[mrow + 48 + l] = f2bf(acc[i][3][r]);
        }
}

// ---------------- flag barrier (R2-proven): no RMW, no acquire-inv ----------------
__device__ __forceinline__ void gbar(int* flags, int e) {
    __syncthreads();   // vmcnt(0): this block's write-through h stores are agent-visible
    if (threadIdx.x == 0)
        __hip_atomic_store(flags + (size_t)blockIdx.x * FLAGSTRIDE, e,
                           __ATOMIC_RELAXED, __HIP_MEMORY_SCOPE_AGENT);
    if (threadIdx.x < 64) {
        for (;;) {
            int v = __hip_atomic_load(flags + (size_t)threadIdx.x * FLAGSTRIDE,
                                      __ATOMIC_RELAXED, __HIP_MEMORY_SCOPE_AGENT);
            if (__all(v >= e)) break;
            __builtin_amdgcn_s_sleep(1);
        }
    }
    __syncthreads();   // compiler memory barrier: h loads below can't hoist above
}

// ---------------- persistent recurrence ----------------
// fresh=1: h_t lives at hbuf + t*128KB (addresses NEVER reused). Any L2 copy is
// therefore necessarily fresh -> consumers use NORMAL CACHED loads; the 8 blocks
// of an XCD share one MALL fill (8MB -> 1MB/step fabric reads, rest L2 hits).
// Producers store write-through no-allocate (sc0 sc1), so no L2 anywhere holds a
// partially-written line. Flag polls stay bypass (polling requires re-reads).
// fresh=0 fallback (small ws): 4-slot ring + bypass reads (R2 semantics).
__global__ __launch_bounds__(256, 1)
void k_rec(const float* __restrict__ W_hh,
           const unsigned short* __restrict__ gib,
           const float* __restrict__ bih, const float* __restrict__ bhh,
           const float* __restrict__ hidden,
           float* __restrict__ out,
           unsigned short* hbuf,
           int* flags,                    // [NBLK*FLAGSTRIDE], zeroed
           int fresh) {
    __shared__ unsigned short sh[49152];  // 96 KB: gates r,z,n for this unit group

    const int tid  = threadIdx.x;
    const int w    = tid >> 6;            // batch quarter 0..3
    const int lane = tid & 63;
    const int q = lane >> 4, l = lane & 15;
    const int G  = blockIdx.x;            // unit group 0..63
    const int m0 = w * 16;
    const int u0 = G * 16 + l;

    // ---- prologue: r,z,n gate fragments -> LDS ([g][kk][lane]*16B) ----
    for (int i = 0; i < 24; ++i) {
        int c  = i * 256 + tid;           // 0..6143
        int g  = c >> 11;                 // 0..2
        int kk = (c >> 6) & 31;
        int ln = c & 63;
        int uu = ln & 15, qq = ln >> 4;
        const float* src = W_hh + (size_t)(g * 1024 + G * 16 + uu) * 1024 + kk * 32 + qq * 8;
        float4 f0 = *(const float4*)src;
        float4 f1 = *(const float4*)(src + 4);
        ushort4 o0, o1;
        o0.x = f2bf(f0.x); o0.y = f2bf(f0.y); o0.z = f2bf(f0.z); o0.w = f2bf(f0.w);
        o1.x = f2bf(f1.x); o1.y = f2bf(f1.y); o1.z = f2bf(f1.z); o1.w = f2bf(f1.w);
        *(ushort4*)&sh[c * 8]     = o0;
        *(ushort4*)&sh[c * 8 + 4] = o1;
    }
    __syncthreads();

    // ---- h0 init + biases; publish h0 into slot 0 (write-through) ----
    float hp[4];
#pragma unroll
    for (int r = 0; r < 4; ++r) {
        int b = m0 + q * 4 + r;
        float hv0 = hidden[(size_t)b * HID + u0];
        hp[r] = hv0;
        stg2_wt(hbuf + (size_t)b * HID + u0, f2bf(hv0));
    }
    float bir = bih[u0], biz = bih[HID + u0], bin = bih[2 * HID + u0];
    float bhr = bhh[u0], bhz = bhh[HID + u0], bhn = bhh[2 * HID + u0];

    // ---- gi for t=0 (b_ih folded in) ----
    float i_r[4], i_z[4], i_n[4];
#pragma unroll
    for (int r = 0; r < 4; ++r) {
        const unsigned short* gp = gib + (size_t)(m0 + q * 4 + r) * N3H + u0;
        i_r[r] = bf2f(gp[0])       + bir;
        i_z[r] = bf2f(gp[HID])     + biz;
        i_n[r] = bf2f(gp[2 * HID]) + bin;
    }

    gbar(flags, 1);   // h0 visible everywhere

    for (int t = 0; t < SEQ; ++t) {
        const int scur = fresh ? t       : (t & (NBUF - 1));
        const int snxt = fresh ? (t + 1) : ((t + 1) & (NBUF - 1));
        const unsigned short* hc = hbuf + (size_t)scur * (BATCH * HID);
        unsigned short*       hn = hbuf + (size_t)snxt * (BATCH * HID);
        const unsigned short* hA = hc + (size_t)(m0 + l) * HID + q * 8;

        // gi(t+1) prefetch (plain cached; retired long before the next drain)
        unsigned short pr[4], pz[4], pn[4];
        if (t + 1 < SEQ) {
            const unsigned short* gt = gib + (size_t)(t + 1) * (BATCH * N3H);
#pragma unroll
            for (int r = 0; r < 4; ++r) {
                const unsigned short* gp = gt + (size_t)(m0 + q * 4 + r) * N3H + u0;
                pr[r] = gp[0]; pz[r] = gp[HID]; pn[r] = gp[2 * HID];
            }
        }

        // ---- h_t -> registers ----
        bhalf8 hv[32];
        if (fresh) {
#pragma unroll
            for (int kk = 0; kk < 32; ++kk)
                hv[kk] = *(const bhalf8*)(hA + kk * 32);   // cached: L2-shared per XCD
        } else {
#pragma unroll
            for (int kk = 0; kk < 32; ++kk)
                hv[kk] = ldg16_bypass(hA + kk * 32);
            VWAIT0();
        }

        // ---- k-loop: pure LDS + MFMA ----
        f32x4 ar = {0.f, 0.f, 0.f, 0.f}, az = ar, an = ar;
#pragma unroll
        for (int kk = 0; kk < 32; ++kk) {
            bhalf8 brf = *(const bhalf8*)&sh[        kk * 512 + lane * 8];
            bhalf8 bzf = *(const bhalf8*)&sh[16384 + kk * 512 + lane * 8];
            bhalf8 bnf = *(const bhalf8*)&sh[32768 + kk * 512 + lane * 8];
            ar = __builtin_amdgcn_mfma_f32_16x16x32_bf16(hv[kk], brf, ar, 0, 0, 0);
            az = __builtin_amdgcn_mfma_f32_16x16x32_bf16(hv[kk], bzf, az, 0, 0, 0);
            an = __builtin_amdgcn_mfma_f32_16x16x32_bf16(hv[kk], bnf, an, 0, 0, 0);
        }

        // ---- gate math; publish h(t+1) immediately (latency-critical) ----
        float osv[4];
#pragma unroll
        for (int r = 0; r < 4; ++r) {
            int b = m0 + q * 4 + r;
            float rr = 1.f / (1.f + __expf(-(i_r[r] + ar[r] + bhr)));
            float zz = 1.f / (1.f + __expf(-(i_z[r] + az[r] + bhz)));
            float nn = tanhf(i_n[r] + rr * (an[r] + bhn));
            float hv2 = (1.f - zz) * nn + zz * hp[r];
            hp[r] = hv2;
            osv[r] = hv2;
            if (t + 1 < SEQ)
                stg2_wt(hn + (size_t)b * HID + u0, f2bf(hv2));
        }

        // fold bias into next step's gi
#pragma unroll
        for (int r = 0; r < 4; ++r) {
            i_r[r] = bf2f(pr[r]) + bir;
            i_z[r] = bf2f(pz[r]) + biz;
            i_n[r] = bf2f(pn[r]) + bin;
        }

        if (t + 1 < SEQ) gbar(flags, t + 2);

        // out stores AFTER the barrier: drain under the next step's work
        float* ot = out + (size_t)t * (BATCH * HID);
#pragma unroll
        for (int r = 0; r < 4; ++r)
            __builtin_nontemporal_store(osv[r], &ot[(size_t)(m0 + q * 4 + r) * HID + u0]);
    }
}

// ---------------- launch ----------------
extern "C" void kernel_launch(void* const* d_in, const int* in_sizes, int n_in,
                              void* d_out, int out_size, void* d_ws, size_t ws_size,
                              hipStream_t stream) {
    (void)in_sizes; (void)n_in; (void)out_size;
    const int*   input  = (const int*)  d_in[0];
    const float* hidden = (const float*)d_in[2];
    const float* emb    = (const float*)d_in[3];
    const float* W_ih   = (const float*)d_in[4];
    const float* W_hh   = (const float*)d_in[5];
    const float* b_ih   = (const float*)d_in[6];
    const float* b_hh   = (const float*)d_in[7];
    float* out = (float*)d_out;

    // workspace layout (bytes)
    const size_t EMB_BF  = 0;                                   // 65,536,000
    const size_t WIH_BF  = EMB_BF + (size_t)VOCAB * EMBD * 2;   // +6,291,456
    const size_t GI_OFF  = WIH_BF + (size_t)N3H * EMBD * 2;     // +201,326,592
    const size_t FLG_OFF = GI_OFF + (size_t)SEQ * BATCH * N3H * 2;
    const size_t H_OFF   = FLG_OFF + (size_t)NBLK * FLAGSTRIDE * 4;
    const size_t NEED_FRESH = H_OFF + (size_t)(SEQ + 1) * BATCH * HID * 2;  // +64MB ring
    const size_t NEED_RING  = H_OFF + (size_t)NBUF * BATCH * HID * 2;
    if (ws_size < NEED_RING) return;
    const int fresh = (ws_size >= NEED_FRESH) ? 1 : 0;

    char* ws = (char*)d_ws;
    unsigned short* embb = (unsigned short*)(ws + EMB_BF);
    unsigned short* wihb = (unsigned short*)(ws + WIH_BF);
    unsigned short* gib  = (unsigned short*)(ws + GI_OFF);
    int*            flags = (int*)(ws + FLG_OFF);
    unsigned short* hbuf = (unsigned short*)(ws + H_OFF);

    hipMemsetAsync(flags, 0, (size_t)NBLK * FLAGSTRIDE * 4, stream);

    {
        int n4 = VOCAB * EMBD / 4;
        k_cvt4<<<(n4 + 255) / 256, 256, 0, stream>>>((const float4*)emb, (ushort4*)embb, n4);
    }
    {
        int n4 = N3H * EMBD / 4;
        k_cvt4<<<(n4 + 255) / 256, 256, 0, stream>>>((const float4*)W_ih, (ushort4*)wihb, n4);
    }

    // input-side GEMM for all timesteps
    k_gi<<<dim3(48, 128), 256, 0, stream>>>(input, embb, wihb, gib);

    // persistent recurrence: 64 blocks (96 KB LDS each -> all co-resident)
    k_rec<<<NBLK, 256, 0, stream>>>(W_hh, gib, b_ih, b_hh, hidden, out, hbuf, flags, fresh);
}

// Round 6
// 4013.679 us; speedup vs baseline: 1.4911x; 1.1395x over previous
//
#include <hip/hip_runtime.h>

// ---------------- types / helpers ----------------
typedef short bhalf8 __attribute__((ext_vector_type(8)));   // 8 bf16 in 4 VGPRs
typedef float f32x4  __attribute__((ext_vector_type(4)));

__device__ __forceinline__ unsigned short f2bf(float f) {
    unsigned int u = __builtin_bit_cast(unsigned int, f);
    u = (u + 0x7fffu + ((u >> 16) & 1u)) >> 16;   // RNE
    return (unsigned short)u;
}
__device__ __forceinline__ float bf2f(unsigned short h) {
    unsigned int u = ((unsigned int)h) << 16;
    return __builtin_bit_cast(float, u);
}

// L2-bypass 16B load (reads the agent coherence point / MALL).
__device__ __forceinline__ bhalf8 ldg16_bypass(const unsigned short* p) {
    bhalf8 r;
    asm volatile("global_load_dwordx4 %0, %1, off sc0 sc1" : "=v"(r) : "v"(p));
    return r;
}
// write-through no-allocate 2B store: agent-visible once vmcnt retires.
__device__ __forceinline__ void stg2_wt(unsigned short* p, unsigned short v) {
    unsigned int vv = v;
    asm volatile("global_store_short %0, %1, off sc0 sc1" :: "v"(p), "v"(vv) : "memory");
}

// counted vmcnt wait; sched_barrier stops hipcc hoisting ops above it (rule #18)
#define VWAIT(N)                                                     \
    do {                                                             \
        asm volatile("s_waitcnt vmcnt(" #N ")" ::: "memory");        \
        __builtin_amdgcn_sched_barrier(0);                           \
    } while (0)

#define SEQ   512
#define BATCH 64
#define HID   1024
#define EMBD  1024
#define VOCAB 32000
#define N3H   3072
#define NBLK  64
#define FLAGSTRIDE 32    // ints; 128B line per flag

// ---------------- fp32 -> bf16 convert (4 elems/thread) ----------------
__global__ void k_cvt4(const float4* __restrict__ in, ushort4* __restrict__ out, int n4) {
    int i = blockIdx.x * blockDim.x + threadIdx.x;
    if (i < n4) {
        float4 v = in[i];
        ushort4 o;
        o.x = f2bf(v.x); o.y = f2bf(v.y); o.z = f2bf(v.z); o.w = f2bf(v.w);
        out[i] = o;
    }
}

// ---------------- gi GEMM: (32768 x 1024) gathered-A  @  W_ih^T -> bf16 ----------------
// 1D grid 6144; XCD-chunked decode: with round-robin workgroup->XCD dispatch,
// ids congruent mod 8 share an XCD. mb = xcd*16 + j/48, nb = j%48 puts ALL 48
// n-blocks of one m-row on ONE XCD -> the 512KB gathered A-tile is fetched into
// that XCD's L2 once and reused 48x (was: re-fetched per nb across XCDs).
__global__ __launch_bounds__(256)
void k_gi(const int* __restrict__ tok, const unsigned short* __restrict__ embb,
          const unsigned short* __restrict__ wih, unsigned short* __restrict__ gi) {
    int g   = blockIdx.x;
    int xcd = g & 7;
    int j   = g >> 3;                 // 0..767
    int mb  = xcd * 16 + (j / 48);    // 0..127
    int nb  = j % 48;                 // 0..47
    int w    = threadIdx.x >> 6;
    int lane = threadIdx.x & 63;
    int q = lane >> 4, l = lane & 15;
    int m0 = mb * 256 + w * 16;
    int n0 = nb * 64;

    const unsigned short* ap[4];
#pragma unroll
    for (int i = 0; i < 4; ++i)
        ap[i] = embb + (size_t)tok[m0 + 64 * i + l] * EMBD + q * 8;

    const unsigned short* bp[4];
#pragma unroll
    for (int jj = 0; jj < 4; ++jj)
        bp[jj] = wih + (size_t)(n0 + 16 * jj + l) * EMBD + q * 8;

    f32x4 acc[4][4];
#pragma unroll
    for (int i = 0; i < 4; ++i)
#pragma unroll
        for (int jj = 0; jj < 4; ++jj)
            acc[i][jj] = (f32x4){0.f, 0.f, 0.f, 0.f};

#pragma unroll 2
    for (int kk = 0; kk < 32; ++kk) {
        int ko = kk * 32;
        bhalf8 bv[4], av[4];
#pragma unroll
        for (int jj = 0; jj < 4; ++jj) bv[jj] = *(const bhalf8*)(bp[jj] + ko);
#pragma unroll
        for (int i = 0; i < 4; ++i) av[i] = *(const bhalf8*)(ap[i] + ko);
#pragma unroll
        for (int i = 0; i < 4; ++i)
#pragma unroll
            for (int jj = 0; jj < 4; ++jj)
                acc[i][jj] = __builtin_amdgcn_mfma_f32_16x16x32_bf16(av[i], bv[jj], acc[i][jj], 0, 0, 0);
    }
#pragma unroll
    for (int i = 0; i < 4; ++i)
#pragma unroll
        for (int r = 0; r < 4; ++r) {
            size_t mrow = (size_t)(m0 + 64 * i + q * 4 + r) * N3H + n0;
            gi[mrow +  0 + l] = f2bf(acc[i][0][r]);
            gi[mrow + 16 + l] = f2bf(acc[i][1][r]);
            gi[mrow + 32 + l] = f2bf(acc[i][2][r]);
            gi[mrow + 48 + l] = f2bf(acc[i][3][r]);
        }
}

// ---------------- flag barrier: no RMW, no acquire-inv, no closing sync ----------------
// Arrive: __syncthreads (each wave drains vmcnt -> its write-through h stores
// are agent-visible), then thread 0 stores the epoch to this block's flag line.
// Detect: EVERY wave's 64 lanes poll all 64 flags; each wave self-releases the
// moment it observes completion (no closing __syncthreads on the critical path).
__device__ __forceinline__ void gbar(int* flags, int e) {
    __syncthreads();
    if (threadIdx.x == 0)
        __hip_atomic_store(flags + (size_t)blockIdx.x * FLAGSTRIDE, e,
                           __ATOMIC_RELAXED, __HIP_MEMORY_SCOPE_AGENT);
    int lane = threadIdx.x & 63;
    for (;;) {
        int v = __hip_atomic_load(flags + (size_t)lane * FLAGSTRIDE,
                                  __ATOMIC_RELAXED, __HIP_MEMORY_SCOPE_AGENT);
        if (__all(v >= e)) break;
        __builtin_amdgcn_s_sleep(1);
    }
}

// ---------------- persistent recurrence (R2 structure + serial-path cuts) ----------------
__global__ __launch_bounds__(256, 1)
void k_rec(const float* __restrict__ W_hh,
           const unsigned short* __restrict__ gib,
           const float* __restrict__ bih, const float* __restrict__ bhh,
           const float* __restrict__ hidden,
           float* __restrict__ out,
           unsigned short* hbuf,          // bf16 [2][64*1024], bypass-only
           int* flags) {                  // [NBLK*FLAGSTRIDE], zeroed
    __shared__ unsigned short sh[32768];  // 64 KB: gates r,z for this unit group

    const int tid  = threadIdx.x;
    const int w    = tid >> 6;            // batch quarter 0..3
    const int lane = tid & 63;
    const int q = lane >> 4, l = lane & 15;
    const int G  = blockIdx.x;            // unit group 0..63
    const int m0 = w * 16;
    const int u0 = G * 16 + l;

    // ---- prologue: r,z gate fragments -> LDS ([g][kk][lane]*16B) ----
    for (int i = 0; i < 16; ++i) {
        int c  = i * 256 + tid;           // 0..4095
        int gg = c >> 11;                 // 0..1
        int kk = (c >> 6) & 31;
        int ln = c & 63;
        int uu = ln & 15, qq = ln >> 4;
        const float* src = W_hh + (size_t)(gg * 1024 + G * 16 + uu) * 1024 + kk * 32 + qq * 8;
        float4 f0 = *(const float4*)src;
        float4 f1 = *(const float4*)(src + 4);
        ushort4 o0, o1;
        o0.x = f2bf(f0.x); o0.y = f2bf(f0.y); o0.z = f2bf(f0.z); o0.w = f2bf(f0.w);
        o1.x = f2bf(f1.x); o1.y = f2bf(f1.y); o1.z = f2bf(f1.z); o1.w = f2bf(f1.w);
        *(ushort4*)&sh[c * 8]     = o0;
        *(ushort4*)&sh[c * 8 + 4] = o1;
    }

    // ---- n-gate fragments in registers ----
    bhalf8 bn[32];
#pragma unroll
    for (int kk = 0; kk < 32; ++kk) {
        const float* src = W_hh + (size_t)(2048 + u0) * 1024 + kk * 32 + q * 8;
        float4 f0 = *(const float4*)src;
        float4 f1 = *(const float4*)(src + 4);
        bhalf8 v;
        v[0] = (short)f2bf(f0.x); v[1] = (short)f2bf(f0.y);
        v[2] = (short)f2bf(f0.z); v[3] = (short)f2bf(f0.w);
        v[4] = (short)f2bf(f1.x); v[5] = (short)f2bf(f1.y);
        v[6] = (short)f2bf(f1.z); v[7] = (short)f2bf(f1.w);
        bn[kk] = v;
    }

    // ---- h0 init + biases (write-through publish) ----
    float hp[4];
#pragma unroll
    for (int r = 0; r < 4; ++r) {
        int b = m0 + q * 4 + r;
        float hv0 = hidden[(size_t)b * HID + u0];
        hp[r] = hv0;
        stg2_wt(hbuf + (size_t)b * HID + u0, f2bf(hv0));
    }
    float bir = bih[u0], biz = bih[HID + u0], bin = bih[2 * HID + u0];
    float bhr = bhh[u0], bhz = bhh[HID + u0], bhn = bhh[2 * HID + u0];

    // ---- gi for t=0 (b_ih folded in) ----
    float i_r[4], i_z[4], i_n[4];
#pragma unroll
    for (int r = 0; r < 4; ++r) {
        const unsigned short* gp = gib + (size_t)(m0 + q * 4 + r) * N3H + u0;
        i_r[r] = bf2f(gp[0])       + bir;
        i_z[r] = bf2f(gp[HID])     + biz;
        i_n[r] = bf2f(gp[2 * HID]) + bin;
    }

    gbar(flags, 1);   // h0 visible everywhere

// h-load group: 8 bypass loads (issue only, no wait)
#define ISSUE8(AV, KB)                                                   \
    _Pragma("unroll")                                                    \
    for (int jj = 0; jj < 8; ++jj) AV[jj] = ldg16_bypass(hA + ((KB) + jj) * 32);

// compute 8 k-slices consuming AV
#define COMPUTE8(AV, KB)                                                 \
    _Pragma("unroll")                                                    \
    for (int jj = 0; jj < 8; ++jj) {                                     \
        int kk = (KB) + jj;                                              \
        bhalf8 brf = *(const bhalf8*)&sh[kk * 512 + lane * 8];           \
        bhalf8 bzf = *(const bhalf8*)&sh[16384 + kk * 512 + lane * 8];   \
        ar = __builtin_amdgcn_mfma_f32_16x16x32_bf16(AV[jj], brf, ar, 0, 0, 0); \
        az = __builtin_amdgcn_mfma_f32_16x16x32_bf16(AV[jj], bzf, az, 0, 0, 0); \
        an = __builtin_amdgcn_mfma_f32_16x16x32_bf16(AV[jj], bn[kk], an, 0, 0, 0); \
    }

    for (int t = 0; t < SEQ; ++t) {
        const unsigned short* hc = hbuf + (size_t)(t & 1) * (BATCH * HID);
        unsigned short*       hn = hbuf + (size_t)((t + 1) & 1) * (BATCH * HID);
        const unsigned short* hA = hc + (size_t)(m0 + l) * HID + q * 8;

        f32x4 ar = {0.f, 0.f, 0.f, 0.f}, az = ar, an = ar;

        // vmcnt == 0 here (the poll's atomic-load waitcnt drained everything).
        // Pinned issue order: h a(8), h b(8), gi(12), [wait20] c(8), [wait20] d(8),
        // [wait8: gi retired], [wait0]. gi drain hides under COMPUTE(a,b).
        bhalf8 ha[8], hb[8];
        ISSUE8(ha, 0)
        ISSUE8(hb, 8)

        unsigned int pr[4], pz[4], pn[4];
        {
            const unsigned short* gt = gib +
                (size_t)((t + 1 < SEQ) ? (t + 1) : t) * (BATCH * N3H);
#pragma unroll
            for (int r = 0; r < 4; ++r) {
                // base at +HID so literal offsets -2048/0/+2048 stay in 13-bit range
                const unsigned short* gp = gt + (size_t)(m0 + q * 4 + r) * N3H + u0 + HID;
                asm volatile("global_load_ushort %0, %1, off offset:-2048" : "=v"(pr[r]) : "v"(gp));
                asm volatile("global_load_ushort %0, %1, off"              : "=v"(pz[r]) : "v"(gp));
                asm volatile("global_load_ushort %0, %1, off offset:2048"  : "=v"(pn[r]) : "v"(gp));
            }
        }

        VWAIT(20);  COMPUTE8(ha, 0)
        ISSUE8(ha, 16)
        VWAIT(20);  COMPUTE8(hb, 8)
        ISSUE8(hb, 24)
        VWAIT(8);   COMPUTE8(ha, 16)   // gi also retired here
        VWAIT(0);   COMPUTE8(hb, 24)

        // ---- gate math; publish h(t+1) immediately (latency-critical) ----
        float osv[4];
#pragma unroll
        for (int r = 0; r < 4; ++r) {
            int b = m0 + q * 4 + r;
            float rr = 1.f / (1.f + __expf(-(i_r[r] + ar[r] + bhr)));
            float zz = 1.f / (1.f + __expf(-(i_z[r] + az[r] + bhz)));
            float targ = i_n[r] + rr * (an[r] + bhn);
            float ex   = __expf(-2.f * targ);            // tanh via one fast exp
            float nn   = (1.f - ex) / (1.f + ex);
            float hv2 = (1.f - zz) * nn + zz * hp[r];
            hp[r] = hv2;
            osv[r] = hv2;
            if (t + 1 < SEQ)
                stg2_wt(hn + (size_t)b * HID + u0, f2bf(hv2));
        }

        // fold bias into next step's gi (gi regs retired at VWAIT(8))
#pragma unroll
        for (int r = 0; r < 4; ++r) {
            i_r[r] = bf2f((unsigned short)pr[r]) + bir;
            i_z[r] = bf2f((unsigned short)pz[r]) + biz;
            i_n[r] = bf2f((unsigned short)pn[r]) + bin;
        }

        if (t + 1 < SEQ) gbar(flags, t + 2);

        // out stores AFTER the barrier: plain (L2-ack), drain under next step
        float* ot = out + (size_t)t * (BATCH * HID);
#pragma unroll
        for (int r = 0; r < 4; ++r)
            ot[(size_t)(m0 + q * 4 + r) * HID + u0] = osv[r];
    }
#undef ISSUE8
#undef COMPUTE8
}

// ---------------- launch ----------------
extern "C" void kernel_launch(void* const* d_in, const int* in_sizes, int n_in,
                              void* d_out, int out_size, void* d_ws, size_t ws_size,
                              hipStream_t stream) {
    (void)in_sizes; (void)n_in; (void)out_size;
    const int*   input  = (const int*)  d_in[0];
    const float* hidden = (const float*)d_in[2];
    const float* emb    = (const float*)d_in[3];
    const float* W_ih   = (const float*)d_in[4];
    const float* W_hh   = (const float*)d_in[5];
    const float* b_ih   = (const float*)d_in[6];
    const float* b_hh   = (const float*)d_in[7];
    float* out = (float*)d_out;

    // workspace layout (bytes)
    const size_t EMB_BF  = 0;                                   // 65,536,000
    const size_t WIH_BF  = EMB_BF + (size_t)VOCAB * EMBD * 2;   // +6,291,456
    const size_t GI_OFF  = WIH_BF + (size_t)N3H * EMBD * 2;     // +201,326,592
    const size_t FLG_OFF = GI_OFF + (size_t)SEQ * BATCH * N3H * 2;
    const size_t H_OFF   = FLG_OFF + (size_t)NBLK * FLAGSTRIDE * 4;
    const size_t NEED    = H_OFF + (size_t)2 * BATCH * HID * 2;
    if (ws_size < NEED) return;

    char* ws = (char*)d_ws;
    unsigned short* embb = (unsigned short*)(ws + EMB_BF);
    unsigned short* wihb = (unsigned short*)(ws + WIH_BF);
    unsigned short* gib  = (unsigned short*)(ws + GI_OFF);
    int*            flags = (int*)(ws + FLG_OFF);
    unsigned short* hbuf = (unsigned short*)(ws + H_OFF);

    hipMemsetAsync(flags, 0, (size_t)NBLK * FLAGSTRIDE * 4, stream);

    {
        int n4 = VOCAB * EMBD / 4;
        k_cvt4<<<(n4 + 255) / 256, 256, 0, stream>>>((const float4*)emb, (ushort4*)embb, n4);
    }
    {
        int n4 = N3H * EMBD / 4;
        k_cvt4<<<(n4 + 255) / 256, 256, 0, stream>>>((const float4*)W_ih, (ushort4*)wihb, n4);
    }

    // input-side GEMM for all timesteps (XCD-chunked 1D grid)
    k_gi<<<6144, 256, 0, stream>>>(input, embb, wihb, gib);

    // persistent recurrence: 64 blocks (64 KB LDS each -> all co-resident)
    k_rec<<<NBLK, 256, 0, stream>>>(W_hh, gib, b_ih, b_hh, hidden, out, hbuf, flags);
}